// Round 1
// baseline (1410.203 us; speedup 1.0000x reference)
//
#include <hip/hip_runtime.h>

// EquivariantSubsample: shifted 2x2 max-pool.
//   images: [B=16, C=64, H=512, W=512] fp32
//   p_w, p_h: [B, C] int32 in {0,1}
//   out: [B, C, 256, 256] fp32
//   out[b,c,oy,ox] = max over 2x2 block at (min(ph+2*oy, H-2), min(pw+2*ox, W-2))
//
// v2 (this round): fully-coalesced loads + deeper MLP + 4x fewer workgroups.
//   - lane t loads float4 at column 4t (wave covers 1KB contiguous per instr;
//     previous version strided 32B/lane -> half-used cache lines).
//   - each wave handles 4 output rows: 16 independent float4 loads in flight
//     per thread before the first waitcnt (was 4).
//   - grid 16384 blocks (was 65536): each block moves 80KB instead of 20KB,
//     amortizing WG launch + scalar p_h/p_w load latency.
//   - pw==1 handled with one __shfl_down per vector + lane-63 fixups;
//     last output column uses clamped pair (510,511), same as verified v1.

#define H 512
#define W 512
#define OH 256
#define OW 256

__global__ __launch_bounds__(256) void equivariant_subsample_kernel(
    const float* __restrict__ img,
    const int* __restrict__ p_w,
    const int* __restrict__ p_h,
    float* __restrict__ out)
{
    const int t  = threadIdx.x;                 // lane 0..63
    const int wy = threadIdx.y;                 // wave 0..3
    const int bc = blockIdx.x >> 4;             // (b*C + c), uniform per block
    const int oy0 = ((blockIdx.x & 15) << 4) + (wy << 2);  // first of 4 output rows

    // Block-uniform -> scalar loads
    const int ph = p_h[bc];
    const int pw = p_w[bc];

    const float* __restrict__ base = img + (size_t)bc * (H * W);
    float* __restrict__ obase = out + (size_t)bc * (OH * OW);

    // Per output row r: input rows y0, y0+1; each row read as two coalesced
    // halves (cols 4t..4t+3 and 256+4t..256+4t+3).
    float4 v0[4], v1[4], v2[4], v3[4];
    #pragma unroll
    for (int r = 0; r < 4; ++r) {
        int y0 = ph + 2 * (oy0 + r);
        if (y0 > H - 2) y0 = H - 2;             // clamp (only ph=1, oy=255)
        const float* row0 = base + (size_t)y0 * W;
        v0[r] = *(const float4*)(row0 + 4 * t);           // row y0,   cols 4t..
        v1[r] = *(const float4*)(row0 + 256 + 4 * t);     // row y0,   cols 256+4t..
        v2[r] = *(const float4*)(row0 + W + 4 * t);       // row y0+1, cols 4t..
        v3[r] = *(const float4*)(row0 + W + 256 + 4 * t); // row y0+1, cols 256+4t..
    }

    if (pw == 0) {
        #pragma unroll
        for (int r = 0; r < 4; ++r) {
            // Pairs: (4t,4t+1) (4t+2,4t+3) per half.
            float2 h0, h1;
            h0.x = fmaxf(fmaxf(v0[r].x, v0[r].y), fmaxf(v2[r].x, v2[r].y));
            h0.y = fmaxf(fmaxf(v0[r].z, v0[r].w), fmaxf(v2[r].z, v2[r].w));
            h1.x = fmaxf(fmaxf(v1[r].x, v1[r].y), fmaxf(v3[r].x, v3[r].y));
            h1.y = fmaxf(fmaxf(v1[r].z, v1[r].w), fmaxf(v3[r].z, v3[r].w));
            float* orow = obase + (size_t)(oy0 + r) * OW;
            *(float2*)(orow + 2 * t)       = h0;   // out cols 2t, 2t+1
            *(float2*)(orow + 128 + 2 * t) = h1;   // out cols 128+2t, 129+2t
        }
    } else {
        // pw == 1. Pairs: (4t+1,4t+2) (4t+3,4t+4) per half.
        #pragma unroll
        for (int r = 0; r < 4; ++r) {
            // Next lane's first element (col 4t+4 / 260+4t), rows y0 and y0+1.
            const float n0 = __shfl_down(v0[r].x, 1);
            const float n2 = __shfl_down(v2[r].x, 1);
            const float n1 = __shfl_down(v1[r].x, 1);
            const float n3 = __shfl_down(v3[r].x, 1);
            // Half-boundary: lane 63 half0 needs col 256 = lane 0's v1/v3 .x.
            const float m0 = __shfl(v1[r].x, 0);
            const float m2 = __shfl(v3[r].x, 0);

            float2 h0, h1;
            // half0: out cols 2t (pair 4t+1,4t+2) and 2t+1 (pair 4t+3,4t+4)
            h0.x = fmaxf(fmaxf(v0[r].y, v0[r].z), fmaxf(v2[r].y, v2[r].z));
            {
                const float e0 = (t == 63) ? m0 : n0;   // col 256 for lane 63
                const float e2 = (t == 63) ? m2 : n2;
                h0.y = fmaxf(fmaxf(v0[r].w, e0), fmaxf(v2[r].w, e2));
            }
            // half1: out cols 128+2t (pair 257+4t,258+4t) and 129+2t
            h1.x = fmaxf(fmaxf(v1[r].y, v1[r].z), fmaxf(v3[r].y, v3[r].z));
            {
                // lane 63 is global last column: clamped pair (510,511) = (.z,.w)
                const float a = (t == 63) ? v1[r].z : v1[r].w;
                const float b = (t == 63) ? v1[r].w : n1;
                const float c = (t == 63) ? v3[r].z : v3[r].w;
                const float d = (t == 63) ? v3[r].w : n3;
                h1.y = fmaxf(fmaxf(a, b), fmaxf(c, d));
            }
            float* orow = obase + (size_t)(oy0 + r) * OW;
            *(float2*)(orow + 2 * t)       = h0;
            *(float2*)(orow + 128 + 2 * t) = h1;
        }
    }
}

extern "C" void kernel_launch(void* const* d_in, const int* in_sizes, int n_in,
                              void* d_out, int out_size, void* d_ws, size_t ws_size,
                              hipStream_t stream) {
    const float* img = (const float*)d_in[0];
    const int* pw = (const int*)d_in[1];
    const int* ph = (const int*)d_in[2];
    float* out = (float*)d_out;

    // 16*64 (b,c) slices * 16 blocks each (16 output rows per block, 4 per wave)
    dim3 grid(16 * 64 * 16);
    dim3 block(64, 4);
    equivariant_subsample_kernel<<<grid, block, 0, stream>>>(img, pw, ph, out);
}